// Round 2
// baseline (30.232 us; speedup 1.0000x reference)
//
#include <hip/hip_runtime.h>

#define D_  128
#define K2_ 256
#define BM  32

typedef short bf16x8 __attribute__((ext_vector_type(8)));
typedef float f32x4  __attribute__((ext_vector_type(4)));

__device__ __forceinline__ unsigned short f2bf(float f) {
  unsigned int u = __float_as_uint(f);
  u += 0x7fffu + ((u >> 16) & 1u);       // round-to-nearest-even
  return (unsigned short)(u >> 16);
}
__device__ __forceinline__ float bf2f(unsigned short s) {
  return __uint_as_float(((unsigned int)s) << 16);
}

__global__ __launch_bounds__(256) void fused_jvp_kernel(
    const float* __restrict__ input_,
    const float* __restrict__ W1, const float* __restrict__ b1,
    const float* __restrict__ W2, const float* __restrict__ b2,
    float* __restrict__ out)
{
  // bf16 LDS tiles, XOR-swizzled: element (row,c) stored at (row*S+c)^((row&7)<<3)
  __shared__ __align__(16) unsigned short xb [BM * D_];   // x hi
  __shared__ __align__(16) unsigned short xlb[BM * D_];   // x lo residual
  __shared__ __align__(16) unsigned short vb [BM * D_];
  __shared__ __align__(16) unsigned short ub [BM * D_];
  __shared__ __align__(16) unsigned short hb [BM * K2_];
  __shared__ __align__(16) unsigned short m2b[BM * K2_];
  __shared__ __align__(16) unsigned short rb [BM * K2_];

  const int tid  = threadIdx.x;
  const int lane = tid & 63;
  const int wv   = tid >> 6;        // wave 0..3
  const int l15  = lane & 15;
  const int lg   = lane >> 4;       // 0..3
  const long rowbase = (long)blockIdx.x * BM;

  // ---- P0: stage x (hi+lo) and v as bf16 (swizzled); out[:, :128] = v (exact f32)
  #pragma unroll
  for (int it = 0; it < 8; ++it) {
    int flat4 = it * 256 + tid;          // float4 index in 32x256 tile
    int row   = flat4 >> 6;              // 64 float4 per row
    int col   = (flat4 & 63) * 4;
    const float4 val = *(const float4*)(input_ + (rowbase + row) * 256 + col);
    ushort4 hq;
    hq.x = f2bf(val.x); hq.y = f2bf(val.y); hq.z = f2bf(val.z); hq.w = f2bf(val.w);
    if (col < D_) {
      ushort4 lq;
      lq.x = f2bf(val.x - bf2f(hq.x));
      lq.y = f2bf(val.y - bf2f(hq.y));
      lq.z = f2bf(val.z - bf2f(hq.z));
      lq.w = f2bf(val.w - bf2f(hq.w));
      int idx = (row * D_ + col) ^ ((row & 7) << 3);
      *(ushort4*)(&xb[idx])  = hq;
      *(ushort4*)(&xlb[idx]) = lq;
    } else {
      int c = col - D_;
      int idx = (row * D_ + c) ^ ((row & 7) << 3);
      *(ushort4*)(&vb[idx]) = hq;
      *(float4*)(out + (rowbase + row) * 256 + c) = val;   // out[:, :128] = v
    }
  }
  __syncthreads();

  // A-fragment from swizzled LDS tile (row-major, stride S elements)
  auto load_afrag = [&](const unsigned short* tile, int S, int rbase, int kbase) -> bf16x8 {
    int row = rbase + l15;
    int idx = (row * S + kbase + lg * 8) ^ ((row & 7) << 3);
    return *(const bf16x8*)(&tile[idx]);
  };
  // B[k][col] = Wp[col*Kd + k]  (k contiguous), hi part only
  auto load_bfrag_row = [&](const float* Wp, int Kd, int colbase, int kbase) -> bf16x8 {
    const float* p = Wp + (size_t)(colbase + l15) * Kd + kbase + lg * 8;
    float4 f0 = *(const float4*)p;
    float4 f1 = *(const float4*)(p + 4);
    bf16x8 r;
    r[0]=(short)f2bf(f0.x); r[1]=(short)f2bf(f0.y); r[2]=(short)f2bf(f0.z); r[3]=(short)f2bf(f0.w);
    r[4]=(short)f2bf(f1.x); r[5]=(short)f2bf(f1.y); r[6]=(short)f2bf(f1.z); r[7]=(short)f2bf(f1.w);
    return r;
  };
  // hi+lo pair for split precision
  auto load_bfrag_row_pair = [&](const float* Wp, int Kd, int colbase, int kbase,
                                 bf16x8* hi, bf16x8* lo) {
    const float* p = Wp + (size_t)(colbase + l15) * Kd + kbase + lg * 8;
    float4 f0 = *(const float4*)p;
    float4 f1 = *(const float4*)(p + 4);
    float fv[8] = {f0.x, f0.y, f0.z, f0.w, f1.x, f1.y, f1.z, f1.w};
    #pragma unroll
    for (int e = 0; e < 8; ++e) {
      unsigned short h = f2bf(fv[e]);
      (*hi)[e] = (short)h;
      (*lo)[e] = (short)f2bf(fv[e] - bf2f(h));
    }
  };
  // B[k][col] = Wp[k*Fd + col]  (k strided)
  auto load_bfrag_T = [&](const float* Wp, int Fd, int colbase, int kbase) -> bf16x8 {
    const float* p = Wp + (size_t)(kbase + lg * 8) * Fd + colbase + l15;
    bf16x8 r;
    #pragma unroll
    for (int e = 0; e < 8; ++e) r[e] = (short)f2bf(p[e * Fd]);
    return r;
  };

  // ---- P1: z1 = x*W1^T + b1 (split precision) ; w = v*W1^T
  f32x4 accz[2][4] = {};
  f32x4 accw[2][4] = {};
  for (int kk = 0; kk < D_; kk += 32) {
    bf16x8 bwh[4], bwl[4];
    #pragma unroll
    for (int nt = 0; nt < 4; ++nt)
      load_bfrag_row_pair(W1, D_, wv * 64 + nt * 16, kk, &bwh[nt], &bwl[nt]);
    #pragma unroll
    for (int mt = 0; mt < 2; ++mt) {
      bf16x8 axh = load_afrag(xb,  D_, mt * 16, kk);
      bf16x8 axl = load_afrag(xlb, D_, mt * 16, kk);
      bf16x8 av  = load_afrag(vb,  D_, mt * 16, kk);
      #pragma unroll
      for (int nt = 0; nt < 4; ++nt) {
        accz[mt][nt] = __builtin_amdgcn_mfma_f32_16x16x32_bf16(axh, bwh[nt], accz[mt][nt], 0, 0, 0);
        accz[mt][nt] = __builtin_amdgcn_mfma_f32_16x16x32_bf16(axh, bwl[nt], accz[mt][nt], 0, 0, 0);
        accz[mt][nt] = __builtin_amdgcn_mfma_f32_16x16x32_bf16(axl, bwh[nt], accz[mt][nt], 0, 0, 0);
        accw[mt][nt] = __builtin_amdgcn_mfma_f32_16x16x32_bf16(av,  bwh[nt], accw[mt][nt], 0, 0, 0);
      }
    }
  }
  #pragma unroll
  for (int mt = 0; mt < 2; ++mt)
  #pragma unroll
  for (int nt = 0; nt < 4; ++nt) {
    int cg = wv * 64 + nt * 16 + l15;
    float bias = b1[cg];
    #pragma unroll
    for (int q = 0; q < 4; ++q) {
      int rg = mt * 16 + lg * 4 + q;
      float z = accz[mt][nt][q] + bias;
      if (__builtin_expect(fabsf(z) < 1e-4f, 0)) {
        // borderline ReLU: recompute exactly in f64 (rare: ~300 of 2.1M elems)
        const float* xr  = input_ + (rowbase + rg) * 256;
        const float* w1r = W1 + (size_t)cg * D_;
        double zd = (double)bias;
        for (int k = 0; k < D_; ++k) zd += (double)xr[k] * (double)w1r[k];
        z = (float)zd;
      }
      float hv = z > 0.f ? z : 0.f;
      float mw = z > 0.f ? accw[mt][nt][q] : 0.f;
      int idx = (rg * K2_ + cg) ^ ((rg & 7) << 3);
      hb[idx]  = f2bf(hv);
      m2b[idx] = f2bf(mw);
    }
  }
  __syncthreads();

  // ---- P2: sdot = h*W2^T ; y = m2*W2^T  (out 32x128, wave owns cols wv*32..+32)
  f32x4 accs[2][2] = {};
  f32x4 accy[2][2] = {};
  for (int kk = 0; kk < K2_; kk += 32) {
    bf16x8 bw[2];
    #pragma unroll
    for (int nt = 0; nt < 2; ++nt) bw[nt] = load_bfrag_row(W2, K2_, wv * 32 + nt * 16, kk);
    #pragma unroll
    for (int mt = 0; mt < 2; ++mt) {
      bf16x8 ah = load_afrag(hb,  K2_, mt * 16, kk);
      bf16x8 am = load_afrag(m2b, K2_, mt * 16, kk);
      #pragma unroll
      for (int nt = 0; nt < 2; ++nt) {
        accs[mt][nt] = __builtin_amdgcn_mfma_f32_16x16x32_bf16(ah, bw[nt], accs[mt][nt], 0, 0, 0);
        accy[mt][nt] = __builtin_amdgcn_mfma_f32_16x16x32_bf16(am, bw[nt], accy[mt][nt], 0, 0, 0);
      }
    }
  }
  float coefr[2][2][4], ginvr[2][2][4];
  #pragma unroll
  for (int mt = 0; mt < 2; ++mt)
  #pragma unroll
  for (int nt = 0; nt < 2; ++nt) {
    int cg = wv * 32 + nt * 16 + l15;
    float bias = b2[cg];
    float sgn  = (cg < 4) ? -1.f : 1.f;
    #pragma unroll
    for (int q = 0; q < 4; ++q) {
      int rg = mt * 16 + lg * 4 + q;
      float sv = 1.f / (1.f + __expf(-(accs[mt][nt][q] + bias)));
      float cf = sgn * sv * (1.f - sv);
      float gi = 1.f / ((sv + 0.618f) * sgn);
      coefr[mt][nt][q] = cf;
      ginvr[mt][nt][q] = gi;
      // exact f32 v from global (L2-hot)
      float vvf = input_[(rowbase + rg) * 256 + 128 + cg];
      int idxd = (rg * D_ + cg) ^ ((rg & 7) << 3);
      ub[idxd] = f2bf(vvf * vvf * cf);          // u = v^2 * coef
    }
  }
  __syncthreads();

  // ---- P3: p = u*W2  (out 32x256) ; r = mask .* p
  f32x4 accp[2][4] = {};
  for (int kk = 0; kk < D_; kk += 32) {
    bf16x8 bw[4];
    #pragma unroll
    for (int nt = 0; nt < 4; ++nt) bw[nt] = load_bfrag_T(W2, K2_, wv * 64 + nt * 16, kk);
    #pragma unroll
    for (int mt = 0; mt < 2; ++mt) {
      bf16x8 au = load_afrag(ub, D_, mt * 16, kk);
      #pragma unroll
      for (int nt = 0; nt < 4; ++nt)
        accp[mt][nt] = __builtin_amdgcn_mfma_f32_16x16x32_bf16(au, bw[nt], accp[mt][nt], 0, 0, 0);
    }
  }
  #pragma unroll
  for (int mt = 0; mt < 2; ++mt)
  #pragma unroll
  for (int nt = 0; nt < 4; ++nt) {
    int cg = wv * 64 + nt * 16 + l15;
    #pragma unroll
    for (int q = 0; q < 4; ++q) {
      int rg = mt * 16 + lg * 4 + q;
      int idx = (rg * K2_ + cg) ^ ((rg & 7) << 3);
      rb[idx] = (hb[idx] != 0) ? f2bf(accp[mt][nt][q]) : (unsigned short)0;
    }
  }
  __syncthreads();

  // ---- P4: t1pre = r*W1  (out 32x128) ; final epilogue
  f32x4 acct[2][2] = {};
  for (int kk = 0; kk < K2_; kk += 32) {
    bf16x8 bw[2];
    #pragma unroll
    for (int nt = 0; nt < 2; ++nt) bw[nt] = load_bfrag_T(W1, D_, wv * 32 + nt * 16, kk);
    #pragma unroll
    for (int mt = 0; mt < 2; ++mt) {
      bf16x8 ar = load_afrag(rb, K2_, mt * 16, kk);
      #pragma unroll
      for (int nt = 0; nt < 2; ++nt)
        acct[mt][nt] = __builtin_amdgcn_mfma_f32_16x16x32_bf16(ar, bw[nt], acct[mt][nt], 0, 0, 0);
    }
  }
  #pragma unroll
  for (int mt = 0; mt < 2; ++mt)
  #pragma unroll
  for (int nt = 0; nt < 2; ++nt) {
    int cg = wv * 32 + nt * 16 + l15;
    #pragma unroll
    for (int q = 0; q < 4; ++q) {
      int rg = mt * 16 + lg * 4 + q;
      float vvf = input_[(rowbase + rg) * 256 + 128 + cg];  // exact f32 v
      float gi  = ginvr[mt][nt][q];
      float dv  = -gi * acct[mt][nt][q]
                + 2.f * vvf * gi * coefr[mt][nt][q] * accy[mt][nt][q];
      out[(rowbase + rg) * 256 + 128 + cg] = dv;
    }
  }
}

extern "C" void kernel_launch(void* const* d_in, const int* in_sizes, int n_in,
                              void* d_out, int out_size, void* d_ws, size_t ws_size,
                              hipStream_t stream) {
  const float* input_ = (const float*)d_in[1];
  const float* W1     = (const float*)d_in[2];
  const float* b1     = (const float*)d_in[3];
  const float* W2     = (const float*)d_in[4];
  const float* b2     = (const float*)d_in[5];
  float* out = (float*)d_out;
  int N = in_sizes[1] / (2 * D_);
  fused_jvp_kernel<<<dim3(N / BM), dim3(256), 0, stream>>>(input_, W1, b1, W2, b2, out);
}